// Round 14
// baseline (133.836 us; speedup 1.0000x reference)
//
#include <hip/hip_runtime.h>
#include <hip/hip_bf16.h>
#include <math.h>

// Problem constants (from reference)
#define BATCH   2
#define SEQ     512     // N
#define DIN     512
#define DM      256     // d_model

#define LOG2E2  2.88539008177792681f   // 2*log2(e)

#if __has_builtin(__builtin_amdgcn_exp2f)
#define EXP2(x) __builtin_amdgcn_exp2f(x)
#else
#define EXP2(x) exp2f(x)
#endif
#if __has_builtin(__builtin_amdgcn_rcpf)
#define RCP(x) __builtin_amdgcn_rcpf(x)
#else
#define RCP(x) (1.0f / (x))
#endif

// tanh(t) with targ = 2*log2(e)*t: tanh = 1 - 2/(1 + exp2(targ)); overflow-safe.
__device__ __forceinline__ float tanh_from_scaled(float targ) {
    return fmaf(-2.0f, RCP(1.0f + EXP2(targ)), 1.0f);
}

// ---------------- Kernel 1: EB4 + (h GEMM + EA fused) ----------------
// 256 blocks x 512 threads.
//  blocks [0,128):   EB4[b][q][j] = {exp2(-c*P_{4q+i}(j))}  (float4, coalesced)
//  blocks [128,256): h tile 32 rows x 64 cols (rt = idx>>2, ct = idx&3).
//    x k-slices staged in LDS (b32 broadcast); Wx read from GLOBAL per k
//    (16.7 MB total, L1-resident 256B segments) -> no b128 LDS tax.
//    EA for the same (row, d) tile computed in the prologue.
__global__ __launch_bounds__(512) void produce_k(
    const float* __restrict__ pos,  // [B, N, 4]
    const float* __restrict__ Wp,   // [4, DM]
    const float* __restrict__ bp,   // [DM]
    const float* __restrict__ x,    // [B*N, DIN]
    const float* __restrict__ Wx,   // [DIN, DM]
    const float* __restrict__ bx,   // [DM]
    float* __restrict__ EA,         // [B*N, DM]
    float4* __restrict__ EB4,       // [B][64][SEQ] float4
    float* __restrict__ h)          // [B*N, DM]
{
    const int tid = threadIdx.x;

    if (blockIdx.x < 128) {
        const int b  = blockIdx.x >> 6;
        const int q  = blockIdx.x & 63;
        const int d0 = 4 * q;
        const float4 p = ((const float4*)pos)[b * SEQ + tid];   // coalesced 16B
        float e[4];
        #pragma unroll
        for (int i = 0; i < 4; i++) {
            const int d = d0 + i;
            const float P = fmaf(p.x, Wp[d], fmaf(p.y, Wp[DM + d],
                            fmaf(p.z, Wp[2*DM + d], p.w * Wp[3*DM + d])));
            e[i] = EXP2(-LOG2E2 * P);
        }
        EB4[((size_t)(b * 64 + q)) * SEQ + tid] = make_float4(e[0], e[1], e[2], e[3]);
        return;
    }

    // ---- h + EA tile ----
    __shared__ float s_xt[32][68];   // 32 rows x 64 k, pad to 68 (8.7 KB)

    const int idx  = blockIdx.x - 128;   // 0..127
    const int rt   = idx >> 2;           // 0..31 row tile
    const int ct   = idx & 3;            // 0..3 col tile
    const int ty   = tid >> 4;           // 0..31 row in tile
    const int tx   = tid & 15;           // 0..15 col quad
    const int row  = rt * 32 + ty;
    const int dcol = ct * 64 + 4 * tx;

    // EA for (row, dcol..dcol+3)
    {
        const float4 p  = ((const float4*)pos)[row];
        const float4 w0 = *(const float4*)(Wp + dcol);
        const float4 w1 = *(const float4*)(Wp + DM + dcol);
        const float4 w2 = *(const float4*)(Wp + 2*DM + dcol);
        const float4 w3 = *(const float4*)(Wp + 3*DM + dcol);
        const float4 bq = *(const float4*)(bp + dcol);
        float4 ea;
        ea.x = EXP2(LOG2E2 * (fmaf(p.x,w0.x,fmaf(p.y,w1.x,fmaf(p.z,w2.x,p.w*w3.x))) + bq.x));
        ea.y = EXP2(LOG2E2 * (fmaf(p.x,w0.y,fmaf(p.y,w1.y,fmaf(p.z,w2.y,p.w*w3.y))) + bq.y));
        ea.z = EXP2(LOG2E2 * (fmaf(p.x,w0.z,fmaf(p.y,w1.z,fmaf(p.z,w2.z,p.w*w3.z))) + bq.z));
        ea.w = EXP2(LOG2E2 * (fmaf(p.x,w0.w,fmaf(p.y,w1.w,fmaf(p.z,w2.w,p.w*w3.w))) + bq.w));
        *(float4*)(EA + (size_t)row * DM + dcol) = ea;
    }

    float4 acc = make_float4(0.f, 0.f, 0.f, 0.f);

    for (int ks = 0; ks < 8; ks++) {
        const int k0 = ks * 64;
        // stage x k-slice: thread (ty, tx) loads its own row's quad (coalesced)
        *(float4*)&s_xt[ty][4 * tx] =
            *(const float4*)(x + (size_t)row * DIN + k0 + 4 * tx);
        __syncthreads();

        const float* __restrict__ wxk = Wx + (size_t)k0 * DM + dcol;
        #pragma unroll 8
        for (int k = 0; k < 64; k++) {
            const float  xv = s_xt[ty][k];                       // b32 broadcast
            const float4 wq = *(const float4*)(wxk + (size_t)k * DM);  // global, L1-hot
            acc.x = fmaf(xv, wq.x, acc.x);
            acc.y = fmaf(xv, wq.y, acc.y);
            acc.z = fmaf(xv, wq.z, acc.z);
            acc.w = fmaf(xv, wq.w, acc.w);
        }
        __syncthreads();
    }

    const float4 bq4 = *(const float4*)(bx + dcol);
    float4 t;
    t.x = tanh_from_scaled(LOG2E2 * (acc.x + bq4.x));
    t.y = tanh_from_scaled(LOG2E2 * (acc.y + bq4.y));
    t.z = tanh_from_scaled(LOG2E2 * (acc.z + bq4.z));
    t.w = tanh_from_scaled(LOG2E2 * (acc.w + bq4.w));
    *(float4*)(h + (size_t)row * DM + dcol) = t;
}

// ---------------- Kernel 2: scores + softmax + weighted sum (fused) ----------------
// 512 blocks (2 i-rows each) x 512 threads (8 waves, 2 blocks/CU).
// Score: thread = j, 64 d-quad iters, 4-way merged rcp (r13-validated body).
// AV: thread = (dq = tid&63 -> 4 d, js = tid>>6 -> 64-j slice); p via LDS
// wave-uniform b128 broadcasts; h via coalesced float4; LDS slice-combine.
__global__ __launch_bounds__(512) void attend_k(
    const int*   __restrict__ mask,  // [B, N, N]
    const float* __restrict__ wv,    // [DM]
    const float* __restrict__ EA,    // [B*N, DM]
    const float4* __restrict__ EB4,  // [B][64][SEQ]
    const float* __restrict__ h,     // [B, N, DM]
    float* __restrict__ out,         // [B, N, DM]
    float* __restrict__ attn_out)    // [B, N, N]
{
    const int b   = blockIdx.x >> 8;
    const int i0  = (blockIdx.x & 255) * 2;
    const int tid = threadIdx.x;             // = j in score phase
    const int l   = tid & 63;

    __shared__ float4 s_eaA[64], s_eaB[64];  // 2 KB
    __shared__ float  s_p[2][SEQ];           // 4 KB
    __shared__ float  s_red[2][8];
    __shared__ float  s_o[7][2][DM];         // 14 KB

    if (tid < 64) {
        s_eaA[tid] = *(const float4*)(EA + (size_t)(b * SEQ + i0) * DM + 4 * tid);
    } else if (tid < 128) {
        s_eaB[tid - 64] = *(const float4*)(EA + (size_t)(b * SEQ + i0 + 1) * DM + 4 * (tid - 64));
    }
    __syncthreads();

    // ---- score: 64 d-quad iters ----
    const float4* __restrict__ EBj = EB4 + (size_t)b * 64 * SEQ + tid;

    float aA = 0.f, aB = 0.f;
    #pragma unroll 8
    for (int q = 0; q < 64; q++) {
        const float4 eb = EBj[(size_t)q * SEQ];   // coalesced dwordx4 (L2)
        const float4 eA = s_eaA[q];               // ds_read_b128 broadcast
        const float4 eB = s_eaB[q];
        const float4 wq = *(const float4*)(wv + 4 * q);   // s_load_dwordx4

        const float yA0 = fmaf(eA.x, eb.x, 1.0f);
        const float yA1 = fmaf(eA.y, eb.y, 1.0f);
        const float yA2 = fmaf(eA.z, eb.z, 1.0f);
        const float yA3 = fmaf(eA.w, eb.w, 1.0f);
        aA = fmaf(fmaf(wq.y, yA0, wq.x * yA1), RCP(yA0 * yA1), aA);
        aA = fmaf(fmaf(wq.w, yA2, wq.z * yA3), RCP(yA2 * yA3), aA);

        const float yB0 = fmaf(eB.x, eb.x, 1.0f);
        const float yB1 = fmaf(eB.y, eb.y, 1.0f);
        const float yB2 = fmaf(eB.z, eb.z, 1.0f);
        const float yB3 = fmaf(eB.w, eb.w, 1.0f);
        aB = fmaf(fmaf(wq.y, yB0, wq.x * yB1), RCP(yB0 * yB1), aB);
        aB = fmaf(fmaf(wq.w, yB2, wq.z * yB3), RCP(yB2 * yB3), aB);
    }

    // ---- masked softmax (score = const - 2a; shift-invariant, exponents O(1)) ----
    const size_t mrowA = (size_t)b * SEQ * SEQ + (size_t)i0 * SEQ + tid;
    const int mA = mask[mrowA];
    const int mB = mask[mrowA + SEQ];
    float pA = mA ? EXP2(-LOG2E2 * aA) : 0.f;
    float pB = mB ? EXP2(-LOG2E2 * aB) : 0.f;

    float sA = pA, sB = pB;
    #pragma unroll
    for (int off = 32; off; off >>= 1) {
        sA += __shfl_xor(sA, off, 64);
        sB += __shfl_xor(sB, off, 64);
    }
    if (l == 0) { s_red[0][tid >> 6] = sA; s_red[1][tid >> 6] = sB; }
    __syncthreads();

    const float4 ra = ((const float4*)s_red[0])[0], rb = ((const float4*)s_red[0])[1];
    const float4 rc = ((const float4*)s_red[1])[0], rd = ((const float4*)s_red[1])[1];
    pA *= __fdividef(1.0f, (ra.x+ra.y+ra.z+ra.w) + (rb.x+rb.y+rb.z+rb.w));
    pB *= __fdividef(1.0f, (rc.x+rc.y+rc.z+rc.w) + (rd.x+rd.y+rd.z+rd.w));

    attn_out[mrowA]       = pA;
    attn_out[mrowA + SEQ] = pB;
    s_p[0][tid] = pA;
    s_p[1][tid] = pB;
    __syncthreads();

    // ---- av: out[i_r, d] = sum_j p_r[j] * h[b,j,d] ----
    const int dq = tid & 63;                                    // 4-d quad
    const int js = __builtin_amdgcn_readfirstlane(tid >> 6);    // 0..7 -> 64-j slice
    const float* __restrict__ hp = h + (size_t)(b * SEQ + js * 64) * DM + 4 * dq;
    const float* __restrict__ p0 = &s_p[0][js * 64];
    const float* __restrict__ p1 = &s_p[1][js * 64];

    float4 a0 = make_float4(0,0,0,0), a1 = a0;
    #pragma unroll 4
    for (int jj = 0; jj < 16; jj++) {
        const float4 P0 = *(const float4*)(p0 + 4 * jj);   // b128 broadcast
        const float4 P1 = *(const float4*)(p1 + 4 * jj);
        const float4 h0 = *(const float4*)(hp + (size_t)(4*jj + 0) * DM);
        const float4 h1 = *(const float4*)(hp + (size_t)(4*jj + 1) * DM);
        const float4 h2 = *(const float4*)(hp + (size_t)(4*jj + 2) * DM);
        const float4 h3 = *(const float4*)(hp + (size_t)(4*jj + 3) * DM);

        a0.x = fmaf(P0.x,h0.x,fmaf(P0.y,h1.x,fmaf(P0.z,h2.x,fmaf(P0.w,h3.x,a0.x))));
        a0.y = fmaf(P0.x,h0.y,fmaf(P0.y,h1.y,fmaf(P0.z,h2.y,fmaf(P0.w,h3.y,a0.y))));
        a0.z = fmaf(P0.x,h0.z,fmaf(P0.y,h1.z,fmaf(P0.z,h2.z,fmaf(P0.w,h3.z,a0.z))));
        a0.w = fmaf(P0.x,h0.w,fmaf(P0.y,h1.w,fmaf(P0.z,h2.w,fmaf(P0.w,h3.w,a0.w))));
        a1.x = fmaf(P1.x,h0.x,fmaf(P1.y,h1.x,fmaf(P1.z,h2.x,fmaf(P1.w,h3.x,a1.x))));
        a1.y = fmaf(P1.x,h0.y,fmaf(P1.y,h1.y,fmaf(P1.z,h2.y,fmaf(P1.w,h3.y,a1.y))));
        a1.z = fmaf(P1.x,h0.z,fmaf(P1.y,h1.z,fmaf(P1.z,h2.z,fmaf(P1.w,h3.z,a1.z))));
        a1.w = fmaf(P1.x,h0.w,fmaf(P1.y,h1.w,fmaf(P1.z,h2.w,fmaf(P1.w,h3.w,a1.w))));
    }

    if (js > 0) {
        *(float4*)&s_o[js - 1][0][4 * dq] = a0;
        *(float4*)&s_o[js - 1][1][4 * dq] = a1;
    }
    __syncthreads();
    if (js == 0) {
        #pragma unroll
        for (int s = 0; s < 7; s++) {
            const float4 q0 = *(const float4*)&s_o[s][0][4 * dq];
            const float4 q1 = *(const float4*)&s_o[s][1][4 * dq];
            a0.x += q0.x; a0.y += q0.y; a0.z += q0.z; a0.w += q0.w;
            a1.x += q1.x; a1.y += q1.y; a1.z += q1.z; a1.w += q1.w;
        }
        float* __restrict__ op = out + (size_t)(b * SEQ + i0) * DM + 4 * dq;
        *(float4*)(op)      = a0;
        *(float4*)(op + DM) = a1;
    }
}

extern "C" void kernel_launch(void* const* d_in, const int* in_sizes, int n_in,
                              void* d_out, int out_size, void* d_ws, size_t ws_size,
                              hipStream_t stream) {
    const float* x    = (const float*)d_in[0];
    const float* pos  = (const float*)d_in[1];
    const int*   mask = (const int*)  d_in[2];
    const float* Wx   = (const float*)d_in[3];
    const float* bx   = (const float*)d_in[4];
    const float* Wp   = (const float*)d_in[5];
    const float* bp   = (const float*)d_in[6];
    const float* wv   = (const float*)d_in[7];

    float* out      = (float*)d_out;                          // [B,N,DM]
    float* attn_out = (float*)d_out + (size_t)BATCH*SEQ*DM;   // [B,N,N]

    char*   ws  = (char*)d_ws;
    float*  h   = (float*)(ws);                               // 1 MB
    float*  EA  = (float*)(ws + (size_t)BATCH*SEQ*DM*4);      // 1 MB
    float4* EB4 = (float4*)(ws + 2*(size_t)BATCH*SEQ*DM*4);   // 1 MB

    produce_k<<<256, 512, 0, stream>>>(pos, Wp, bp, x, Wx, bx, EA, EB4, h);
    attend_k <<<(BATCH*SEQ)/2, 512, 0, stream>>>(mask, wv, EA, EB4, h, out, attn_out);
}

// Round 15
// 114.447 us; speedup vs baseline: 1.1694x; 1.1694x over previous
//
#include <hip/hip_runtime.h>
#include <hip/hip_bf16.h>
#include <math.h>

// Problem constants (from reference)
#define BATCH   2
#define SEQ     512     // N
#define DIN     512
#define DM      256     // d_model

#define LOG2E2  2.88539008177792681f   // 2*log2(e)

#if __has_builtin(__builtin_amdgcn_exp2f)
#define EXP2(x) __builtin_amdgcn_exp2f(x)
#else
#define EXP2(x) exp2f(x)
#endif
#if __has_builtin(__builtin_amdgcn_rcpf)
#define RCP(x) __builtin_amdgcn_rcpf(x)
#else
#define RCP(x) (1.0f / (x))
#endif

// tanh(t) with targ = 2*log2(e)*t: tanh = 1 - 2/(1 + exp2(targ)); overflow-safe.
__device__ __forceinline__ float tanh_from_scaled(float targ) {
    return fmaf(-2.0f, RCP(1.0f + EXP2(targ)), 1.0f);
}

// ---------------- Kernel 1: EB4 quads + EA rows (r13-verified) ----------------
// 640 blocks x 512 threads.
//  blocks [0,128):   EB4[b][q][j] = {exp2(-c*P_{4q+i}(j))}  (float4, coalesced)
//  blocks [128,640): EA[row][d] = exp2(c*(P_d(row)+bp_d)), 2 rows/block, coalesced.
__global__ __launch_bounds__(512) void pre_k(
    const float* __restrict__ pos,  // [B, N, 4]
    const float* __restrict__ Wp,   // [4, DM]
    const float* __restrict__ bp,   // [DM]
    float* __restrict__ EA,         // [B*N, DM]
    float4* __restrict__ EB4)       // [B][64][SEQ] float4
{
    const int tid = threadIdx.x;

    if (blockIdx.x < 128) {
        const int b  = blockIdx.x >> 6;
        const int q  = blockIdx.x & 63;
        const int d0 = 4 * q;
        const float4 p = ((const float4*)pos)[b * SEQ + tid];   // coalesced 16B
        float e[4];
        #pragma unroll
        for (int i = 0; i < 4; i++) {
            const int d = d0 + i;
            const float P = fmaf(p.x, Wp[d], fmaf(p.y, Wp[DM + d],
                            fmaf(p.z, Wp[2*DM + d], p.w * Wp[3*DM + d])));
            e[i] = EXP2(-LOG2E2 * P);
        }
        EB4[((size_t)(b * 64 + q)) * SEQ + tid] = make_float4(e[0], e[1], e[2], e[3]);
        return;
    }

    // EA part: 2 rows/block
    const int idx = blockIdx.x - 128;          // 0..511
    const int r2  = __builtin_amdgcn_readfirstlane(tid >> 8);   // 0/1
    const int d   = tid & 255;
    const int row = idx * 2 + r2;
    const float4 p = ((const float4*)pos)[row];   // uniform -> s_load
    const float P = fmaf(p.x, Wp[d],
                    fmaf(p.y, Wp[DM + d],
                    fmaf(p.z, Wp[2*DM + d],
                         p.w * Wp[3*DM + d])));
    EA[(size_t)row * DM + d] = EXP2(LOG2E2 * (P + bp[d]));   // coalesced
}

// ---------------- Kernel 2: h = tanh(x@Wx + bx), tiled GEMM (r13-verified) ----------
// 256 blocks = 32 row-tiles x 8 col-tiles (32x32 output tile), 256 threads.
// thread = (tx = tid&7 -> 4 cols, ty = tid>>3 -> row). K staged in LDS, 8 steps of 64.
// Wx+X L2 traffic: 33 MB total.
__global__ __launch_bounds__(256) void h_k(
    const float* __restrict__ x,    // [B*N, DIN]
    const float* __restrict__ Wx,   // [DIN, DM]
    const float* __restrict__ bx,   // [DM]
    float* __restrict__ h)          // [B*N, DM]
{
    __shared__ float s_xt[32][68];   // 32 rows x 64 k, stride 68 (16B-aligned, bank-safe)
    __shared__ float s_wt[64][32];   // 64 k x 32 cols

    const int tid = threadIdx.x;
    const int rt  = blockIdx.x >> 3;
    const int ct  = blockIdx.x & 7;
    const int tx  = tid & 7;         // col quad
    const int ty  = tid >> 3;        // row 0..31

    float4 acc = make_float4(0.f, 0.f, 0.f, 0.f);

    for (int ks = 0; ks < 8; ks++) {
        const int k0 = ks * 64;
        // stage X tile: 32 rows x 16 float4
        #pragma unroll
        for (int s = 0; s < 2; s++) {
            const int fidx = tid * 2 + s;
            const int r = fidx >> 4, c = fidx & 15;
            const float4 v = *(const float4*)(x + (size_t)(rt * 32 + r) * DIN + k0 + 4 * c);
            *(float4*)&s_xt[r][4 * c] = v;
        }
        // stage Wx tile: 64 k x 8 float4
        #pragma unroll
        for (int s = 0; s < 2; s++) {
            const int fidx = tid * 2 + s;
            const int r = fidx >> 3, c = fidx & 7;
            *(float4*)&s_wt[r][4 * c] =
                *(const float4*)(Wx + (size_t)(k0 + r) * DM + ct * 32 + 4 * c);
        }
        __syncthreads();

        #pragma unroll 8
        for (int k = 0; k < 64; k++) {
            const float  xv = s_xt[ty][k];                  // b32, bank-staggered by ty
            const float4 wq = *(const float4*)&s_wt[k][4 * tx];  // b128, conflict-free
            acc.x = fmaf(xv, wq.x, acc.x);
            acc.y = fmaf(xv, wq.y, acc.y);
            acc.z = fmaf(xv, wq.z, acc.z);
            acc.w = fmaf(xv, wq.w, acc.w);
        }
        __syncthreads();
    }

    const float4 bq = *(const float4*)(bx + ct * 32 + 4 * tx);
    float4 t;
    t.x = tanh_from_scaled(LOG2E2 * (acc.x + bq.x));
    t.y = tanh_from_scaled(LOG2E2 * (acc.y + bq.y));
    t.z = tanh_from_scaled(LOG2E2 * (acc.z + bq.z));
    t.w = tanh_from_scaled(LOG2E2 * (acc.w + bq.w));
    *(float4*)(h + (size_t)(rt * 32 + ty) * DM + ct * 32 + 4 * tx) = t;
}

// ---------------- Kernel 3: scores + softmax + weighted sum (r14-verified) ----------
// 512 blocks (2 i-rows each) x 512 threads (8 waves, 2 blocks/CU).
__global__ __launch_bounds__(512) void attend_k(
    const int*   __restrict__ mask,  // [B, N, N]
    const float* __restrict__ wv,    // [DM]
    const float* __restrict__ EA,    // [B*N, DM]
    const float4* __restrict__ EB4,  // [B][64][SEQ]
    const float* __restrict__ h,     // [B, N, DM]
    float* __restrict__ out,         // [B, N, DM]
    float* __restrict__ attn_out)    // [B, N, N]
{
    const int b   = blockIdx.x >> 8;
    const int i0  = (blockIdx.x & 255) * 2;
    const int tid = threadIdx.x;             // = j in score phase
    const int l   = tid & 63;

    __shared__ float4 s_eaA[64], s_eaB[64];  // 2 KB
    __shared__ float  s_p[2][SEQ];           // 4 KB
    __shared__ float  s_red[2][8];
    __shared__ float  s_o[7][2][DM];         // 14 KB

    if (tid < 64) {
        s_eaA[tid] = *(const float4*)(EA + (size_t)(b * SEQ + i0) * DM + 4 * tid);
    } else if (tid < 128) {
        s_eaB[tid - 64] = *(const float4*)(EA + (size_t)(b * SEQ + i0 + 1) * DM + 4 * (tid - 64));
    }
    __syncthreads();

    // ---- score: 64 d-quad iters, 4-way merged rcp ----
    const float4* __restrict__ EBj = EB4 + (size_t)b * 64 * SEQ + tid;

    float aA = 0.f, aB = 0.f;
    #pragma unroll 8
    for (int q = 0; q < 64; q++) {
        const float4 eb = EBj[(size_t)q * SEQ];   // coalesced dwordx4 (L2)
        const float4 eA = s_eaA[q];               // ds_read_b128 broadcast
        const float4 eB = s_eaB[q];
        const float4 wq = *(const float4*)(wv + 4 * q);   // s_load_dwordx4

        const float yA0 = fmaf(eA.x, eb.x, 1.0f);
        const float yA1 = fmaf(eA.y, eb.y, 1.0f);
        const float yA2 = fmaf(eA.z, eb.z, 1.0f);
        const float yA3 = fmaf(eA.w, eb.w, 1.0f);
        aA = fmaf(fmaf(wq.y, yA0, wq.x * yA1), RCP(yA0 * yA1), aA);
        aA = fmaf(fmaf(wq.w, yA2, wq.z * yA3), RCP(yA2 * yA3), aA);

        const float yB0 = fmaf(eB.x, eb.x, 1.0f);
        const float yB1 = fmaf(eB.y, eb.y, 1.0f);
        const float yB2 = fmaf(eB.z, eb.z, 1.0f);
        const float yB3 = fmaf(eB.w, eb.w, 1.0f);
        aB = fmaf(fmaf(wq.y, yB0, wq.x * yB1), RCP(yB0 * yB1), aB);
        aB = fmaf(fmaf(wq.w, yB2, wq.z * yB3), RCP(yB2 * yB3), aB);
    }

    // ---- masked softmax (score = const - 2a; shift-invariant, exponents O(1)) ----
    const size_t mrowA = (size_t)b * SEQ * SEQ + (size_t)i0 * SEQ + tid;
    const int mA = mask[mrowA];
    const int mB = mask[mrowA + SEQ];
    float pA = mA ? EXP2(-LOG2E2 * aA) : 0.f;
    float pB = mB ? EXP2(-LOG2E2 * aB) : 0.f;

    float sA = pA, sB = pB;
    #pragma unroll
    for (int off = 32; off; off >>= 1) {
        sA += __shfl_xor(sA, off, 64);
        sB += __shfl_xor(sB, off, 64);
    }
    if (l == 0) { s_red[0][tid >> 6] = sA; s_red[1][tid >> 6] = sB; }
    __syncthreads();

    const float4 ra = ((const float4*)s_red[0])[0], rb = ((const float4*)s_red[0])[1];
    const float4 rc = ((const float4*)s_red[1])[0], rd = ((const float4*)s_red[1])[1];
    pA *= __fdividef(1.0f, (ra.x+ra.y+ra.z+ra.w) + (rb.x+rb.y+rb.z+rb.w));
    pB *= __fdividef(1.0f, (rc.x+rc.y+rc.z+rc.w) + (rd.x+rd.y+rd.z+rd.w));

    attn_out[mrowA]       = pA;
    attn_out[mrowA + SEQ] = pB;
    s_p[0][tid] = pA;
    s_p[1][tid] = pB;
    __syncthreads();

    // ---- av: out[i_r, d] = sum_j p_r[j] * h[b,j,d] ----
    const int dq = tid & 63;                                    // 4-d quad
    const int js = __builtin_amdgcn_readfirstlane(tid >> 6);    // 0..7 -> 64-j slice
    const float* __restrict__ hp = h + (size_t)(b * SEQ + js * 64) * DM + 4 * dq;
    const float* __restrict__ p0 = &s_p[0][js * 64];
    const float* __restrict__ p1 = &s_p[1][js * 64];

    float4 a0 = make_float4(0,0,0,0), a1 = a0;
    #pragma unroll 4
    for (int jj = 0; jj < 16; jj++) {
        const float4 P0 = *(const float4*)(p0 + 4 * jj);   // b128 broadcast
        const float4 P1 = *(const float4*)(p1 + 4 * jj);
        const float4 h0 = *(const float4*)(hp + (size_t)(4*jj + 0) * DM);
        const float4 h1 = *(const float4*)(hp + (size_t)(4*jj + 1) * DM);
        const float4 h2 = *(const float4*)(hp + (size_t)(4*jj + 2) * DM);
        const float4 h3 = *(const float4*)(hp + (size_t)(4*jj + 3) * DM);

        a0.x = fmaf(P0.x,h0.x,fmaf(P0.y,h1.x,fmaf(P0.z,h2.x,fmaf(P0.w,h3.x,a0.x))));
        a0.y = fmaf(P0.x,h0.y,fmaf(P0.y,h1.y,fmaf(P0.z,h2.y,fmaf(P0.w,h3.y,a0.y))));
        a0.z = fmaf(P0.x,h0.z,fmaf(P0.y,h1.z,fmaf(P0.z,h2.z,fmaf(P0.w,h3.z,a0.z))));
        a0.w = fmaf(P0.x,h0.w,fmaf(P0.y,h1.w,fmaf(P0.z,h2.w,fmaf(P0.w,h3.w,a0.w))));
        a1.x = fmaf(P1.x,h0.x,fmaf(P1.y,h1.x,fmaf(P1.z,h2.x,fmaf(P1.w,h3.x,a1.x))));
        a1.y = fmaf(P1.x,h0.y,fmaf(P1.y,h1.y,fmaf(P1.z,h2.y,fmaf(P1.w,h3.y,a1.y))));
        a1.z = fmaf(P1.x,h0.z,fmaf(P1.y,h1.z,fmaf(P1.z,h2.z,fmaf(P1.w,h3.z,a1.z))));
        a1.w = fmaf(P1.x,h0.w,fmaf(P1.y,h1.w,fmaf(P1.z,h2.w,fmaf(P1.w,h3.w,a1.w))));
    }

    if (js > 0) {
        *(float4*)&s_o[js - 1][0][4 * dq] = a0;
        *(float4*)&s_o[js - 1][1][4 * dq] = a1;
    }
    __syncthreads();
    if (js == 0) {
        #pragma unroll
        for (int s = 0; s < 7; s++) {
            const float4 q0 = *(const float4*)&s_o[s][0][4 * dq];
            const float4 q1 = *(const float4*)&s_o[s][1][4 * dq];
            a0.x += q0.x; a0.y += q0.y; a0.z += q0.z; a0.w += q0.w;
            a1.x += q1.x; a1.y += q1.y; a1.z += q1.z; a1.w += q1.w;
        }
        float* __restrict__ op = out + (size_t)(b * SEQ + i0) * DM + 4 * dq;
        *(float4*)(op)      = a0;
        *(float4*)(op + DM) = a1;
    }
}

extern "C" void kernel_launch(void* const* d_in, const int* in_sizes, int n_in,
                              void* d_out, int out_size, void* d_ws, size_t ws_size,
                              hipStream_t stream) {
    const float* x    = (const float*)d_in[0];
    const float* pos  = (const float*)d_in[1];
    const int*   mask = (const int*)  d_in[2];
    const float* Wx   = (const float*)d_in[3];
    const float* bx   = (const float*)d_in[4];
    const float* Wp   = (const float*)d_in[5];
    const float* bp   = (const float*)d_in[6];
    const float* wv   = (const float*)d_in[7];

    float* out      = (float*)d_out;                          // [B,N,DM]
    float* attn_out = (float*)d_out + (size_t)BATCH*SEQ*DM;   // [B,N,N]

    char*   ws  = (char*)d_ws;
    float*  h   = (float*)(ws);                               // 1 MB
    float*  EA  = (float*)(ws + (size_t)BATCH*SEQ*DM*4);      // 1 MB
    float4* EB4 = (float4*)(ws + 2*(size_t)BATCH*SEQ*DM*4);   // 1 MB

    pre_k   <<<128 + (BATCH*SEQ)/2, 512, 0, stream>>>(pos, Wp, bp, EA, EB4);
    h_k     <<<256, 256, 0, stream>>>(x, Wx, bx, h);
    attend_k<<<(BATCH*SEQ)/2, 512, 0, stream>>>(mask, wv, EA, EB4, h, out, attn_out);
}